// Round 6
// baseline (2254.738 us; speedup 1.0000x reference)
//
#include <hip/hip_runtime.h>

// Nearest-centroid assignment, bit-exact replication of the numpy reference.
//   dot  : np.einsum contig_outstride0_two — baseline SSE3 npyv path:
//          4-lane vacc, 16-float blocks ascending, within-block reversed
//          muladd cascade vacc = p0+(p1+(p2+(p3+vacc))), mul/add SEPARATELY
//          rounded (no FMA in baseline), SSE3 hadd horizontal (A0+A1)+(A2+A3).
//   norms: np.sum pairwise — AVX512F dispatched base case:
//          n=256 -> 128+128; per 128: r_j[i] = q[16j+i] + q[64+16j+i] (j=0..3,
//          16 lanes), lane-wise (r0+r1)+(r2+r3), then _mm512_reduce_add_ps
//          fold-by-halves (+8, +4, +2, +1).
//   sim  : fl32( fl32( fl32(2*dot) - xn ) - cn ), argmax = first max.
// All exact-path fp ops via __fmul_rn/__fadd_rn/__fsub_rn (cannot contract).
// out[0..N) = max_sim (float), out[N..2N) = argmax (stored as float)
constexpr int N = 131072;
constexpr int D = 256;
constexpr int K = 1024;

constexpr int TM = 32;    // rows per block
constexpr int TK = 128;   // centroids per chunk
constexpr int TD = 64;    // depth per stage
constexpr int LPAD = 68;  // leading dim pad

__device__ __forceinline__ float sqf(float a) { return __fmul_rn(a, a); }

// numpy AVX512F pairwise base case over 128 contiguous squares.
__device__ __forceinline__ float np_sumsq128(const float* __restrict__ q) {
    float lane[16];
#pragma unroll
    for (int j = 0; j < 16; j++) {
        const float r0 = __fadd_rn(sqf(q[j]),      sqf(q[64 + j]));
        const float r1 = __fadd_rn(sqf(q[16 + j]), sqf(q[80 + j]));
        const float r2 = __fadd_rn(sqf(q[32 + j]), sqf(q[96 + j]));
        const float r3 = __fadd_rn(sqf(q[48 + j]), sqf(q[112 + j]));
        lane[j] = __fadd_rn(__fadd_rn(r0, r1), __fadd_rn(r2, r3));
    }
    float t[8];
#pragma unroll
    for (int i = 0; i < 8; i++) t[i] = __fadd_rn(lane[i], lane[i + 8]);
    float u[4];
#pragma unroll
    for (int i = 0; i < 4; i++) u[i] = __fadd_rn(t[i], t[i + 4]);
    return __fadd_rn(__fadd_rn(u[0], u[2]), __fadd_rn(u[1], u[3]));
}

// np.sum(v*v, axis=-1) for a 256-float row: pairwise split 128+128.
__device__ __forceinline__ float np_pw256_sq(const float* __restrict__ p) {
    return __fadd_rn(np_sumsq128(p), np_sumsq128(p + 128));
}

__global__ __launch_bounds__(256) void cnorm_kernel(const float* __restrict__ c,
                                                    float* __restrict__ cn) {
    const int k = blockIdx.x * 256 + threadIdx.x;
    if (k < K) cn[k] = np_pw256_sq(c + (size_t)k * D);
}

__global__ __launch_bounds__(256) void assign_kernel(const float* __restrict__ x,
                                                     const float* __restrict__ c,
                                                     const float* __restrict__ cn,
                                                     float* __restrict__ out) {
    __shared__ float xL[TM][LPAD];   // [n][d], row-major
    __shared__ float cL[TK][LPAD];   // [k][d], row-major
    __shared__ float xn_sh[TM];
    __shared__ float rmaxs[4][TM];
    __shared__ int   ridxs[4][TM];

    const int t    = threadIdx.x;
    const int w    = t >> 6;      // wave [0,4)
    const int lane = t & 63;
    const int rg   = lane >> 3;   // row group [0,8): rows 4*rg..4*rg+3
    const int kq   = lane & 7;    // k group within wave [0,8)
    const int kb   = 32 * w + 4 * kq;  // k base within chunk
    const int n0   = blockIdx.x * TM;

    if (t < TM) xn_sh[t] = np_pw256_sq(x + (size_t)(n0 + t) * D);
    __syncthreads();

    float xnr[4];
#pragma unroll
    for (int r = 0; r < 4; r++) xnr[r] = xn_sh[4 * rg + r];

    float runv[4];
    int   runi[4];
#pragma unroll
    for (int r = 0; r < 4; r++) { runv[r] = -__builtin_inff(); runi[r] = 0x7fffffff; }

    for (int kc = 0; kc < K; kc += TK) {
        // SSE 4-lane accumulators per (row, k): A[r][q][j], j = d mod 4
        float A[4][4][4];
#pragma unroll
        for (int r = 0; r < 4; r++)
#pragma unroll
            for (int q = 0; q < 4; q++)
#pragma unroll
                for (int j = 0; j < 4; j++) A[r][q][j] = 0.f;

        for (int dc = 0; dc < D; dc += TD) {
            // ---- stage x tile: 32 rows x 64 floats ----
            {
                const int row = t >> 3;   // [0,32)
                const int f0  = t & 7;    // [0,8)
                const float* src = x + (size_t)(n0 + row) * D + dc;
                const float4 v0 = ((const float4*)src)[f0];
                const float4 v1 = ((const float4*)src)[f0 + 8];
                *(float4*)&xL[row][4 * f0]       = v0;
                *(float4*)&xL[row][4 * (f0 + 8)] = v1;
            }
            // ---- stage c tile: 128 rows x 64 floats ----
            {
                const int row = t >> 1;   // [0,128)
                const int c2  = t & 1;
                const float* src = c + (size_t)(kc + row) * D + dc;
#pragma unroll
                for (int i = 0; i < 8; i++) {
                    const int f = c2 + 2 * i;
                    *(float4*)&cL[row][4 * f] = ((const float4*)src)[f];
                }
            }
            __syncthreads();

            // numpy einsum order: 16-float blocks ascending, sub-vectors i = 3..0,
            // each product added to the running 4-lane accumulator (unfused).
#pragma unroll
            for (int tb = 0; tb < 4; tb++) {
#pragma unroll
                for (int i = 3; i >= 0; i--) {
                    const int d0 = 16 * tb + 4 * i;
                    float4 xv[4], cv[4];
#pragma unroll
                    for (int r = 0; r < 4; r++) xv[r] = *(const float4*)&xL[4 * rg + r][d0];
#pragma unroll
                    for (int q = 0; q < 4; q++) cv[q] = *(const float4*)&cL[kb + q][d0];
#pragma unroll
                    for (int r = 0; r < 4; r++)
#pragma unroll
                        for (int q = 0; q < 4; q++) {
                            A[r][q][0] = __fadd_rn(A[r][q][0], __fmul_rn(xv[r].x, cv[q].x));
                            A[r][q][1] = __fadd_rn(A[r][q][1], __fmul_rn(xv[r].y, cv[q].y));
                            A[r][q][2] = __fadd_rn(A[r][q][2], __fmul_rn(xv[r].z, cv[q].z));
                            A[r][q][3] = __fadd_rn(A[r][q][3], __fmul_rn(xv[r].w, cv[q].w));
                        }
                }
            }
            __syncthreads();
        }

        // ---- chunk epilogue ----
        float cnv[4];
#pragma unroll
        for (int q = 0; q < 4; q++) cnv[q] = cn[kc + kb + q];

#pragma unroll
        for (int r = 0; r < 4; r++) {
            float bv = -__builtin_inff();
            int   bi = 0x7fffffff;
#pragma unroll
            for (int q = 0; q < 4; q++) {
                // SSE3 hadd horizontal: (A0+A1)+(A2+A3)
                const float dot = __fadd_rn(__fadd_rn(A[r][q][0], A[r][q][1]),
                                            __fadd_rn(A[r][q][2], A[r][q][3]));
                float v = __fmul_rn(2.0f, dot);
                v = __fsub_rn(v, xnr[r]);
                v = __fsub_rn(v, cnv[q]);
                const int kg = kc + kb + q;
                if (v > bv) { bv = v; bi = kg; }  // ascending scan: strict > = first max
            }
#pragma unroll
            for (int m = 1; m <= 4; m <<= 1) {
                const float ov = __shfl_xor(bv, m);
                const int   oi = __shfl_xor(bi, m);
                if (ov > bv || (ov == bv && oi < bi)) { bv = ov; bi = oi; }
            }
            if (kq == 0) {
                if (bv > runv[r] || (bv == runv[r] && bi < runi[r])) {
                    runv[r] = bv; runi[r] = bi;
                }
            }
        }
    }

    // ---- cross-wave merge + store ----
    if (kq == 0) {
#pragma unroll
        for (int r = 0; r < 4; r++) {
            rmaxs[w][4 * rg + r] = runv[r];
            ridxs[w][4 * rg + r] = runi[r];
        }
    }
    __syncthreads();

    if (t < TM) {
        float bv = rmaxs[0][t];
        int   bi = ridxs[0][t];
#pragma unroll
        for (int ww = 1; ww < 4; ww++) {
            const float ov = rmaxs[ww][t];
            const int   oi = ridxs[ww][t];
            if (ov > bv || (ov == bv && oi < bi)) { bv = ov; bi = oi; }
        }
        out[n0 + t]     = bv;         // np-bit-exact sim -> np.max bits
        out[N + n0 + t] = (float)bi;
    }
}

extern "C" void kernel_launch(void* const* d_in, const int* in_sizes, int n_in,
                              void* d_out, int out_size, void* d_ws, size_t ws_size,
                              hipStream_t stream) {
    const float* x = (const float*)d_in[0];
    const float* c = (const float*)d_in[1];
    float* out     = (float*)d_out;
    float* cn      = (float*)d_ws;  // K floats

    cnorm_kernel<<<(K + 255) / 256, 256, 0, stream>>>(c, cn);
    assign_kernel<<<N / TM, 256, 0, stream>>>(x, c, cn, out);
}

// Round 7
// 1703.871 us; speedup vs baseline: 1.3233x; 1.3233x over previous
//
#include <hip/hip_runtime.h>

// Nearest-centroid assignment. out[0..N) = max_sim (float), out[N..2N) = argmax (as float).
//
// Decision semantics = round-6 validated np bit-model:
//   dot  : einsum baseline-SSE3: 4-lane vacc, 16-blocks ascending, sub-vecs i=3..0,
//          unfused mul/add, hadd horizontal (A0+A1)+(A2+A3)
//   norms: np.sum pairwise AVX512F base case
//   sim  : fl32(fl32(fl32(2*dot)-xn)-cn), argmax = first max
//
// Speed: fast fp32-FMA GEMM computes top1(value,index)+top2(value) per row.
// margin >= EPS  -> np winner provably == fast winner (error bound ~0.013 per side);
//                   recompute winner's sim np-bit-exactly, write out.
// margin <  EPS  -> row queued; fallback kernel redoes full np-bit-exact 1024-way
//                   argmax (identical to the round-6 kernel's semantics).
constexpr int N = 131072;
constexpr int D = 256;
constexpr int K = 1024;

constexpr int TM = 64;    // rows per block (fast kernel)
constexpr int TK = 128;   // centroids per chunk
constexpr int TD = 64;    // depth per stage
constexpr int XPAD = 68;
constexpr int CPAD = 132;
constexpr float EPS = 0.08f;

typedef float v2f __attribute__((ext_vector_type(2)));

__device__ __forceinline__ float sqf(float a) { return __fmul_rn(a, a); }

// numpy AVX512F pairwise base case over 128 contiguous squares.
__device__ __forceinline__ float np_sumsq128(const float* q) {
    float lane[16];
#pragma unroll
    for (int j = 0; j < 16; j++) {
        const float r0 = __fadd_rn(sqf(q[j]),      sqf(q[64 + j]));
        const float r1 = __fadd_rn(sqf(q[16 + j]), sqf(q[80 + j]));
        const float r2 = __fadd_rn(sqf(q[32 + j]), sqf(q[96 + j]));
        const float r3 = __fadd_rn(sqf(q[48 + j]), sqf(q[112 + j]));
        lane[j] = __fadd_rn(__fadd_rn(r0, r1), __fadd_rn(r2, r3));
    }
    float t[8];
#pragma unroll
    for (int i = 0; i < 8; i++) t[i] = __fadd_rn(lane[i], lane[i + 8]);
    float u[4];
#pragma unroll
    for (int i = 0; i < 4; i++) u[i] = __fadd_rn(t[i], t[i + 4]);
    return __fadd_rn(__fadd_rn(u[0], u[2]), __fadd_rn(u[1], u[3]));
}
__device__ __forceinline__ float np_pw256_sq(const float* p) {
    return __fadd_rn(np_sumsq128(p), np_sumsq128(p + 128));
}

// np einsum bit-exact dot over 256 contiguous floats.
__device__ __forceinline__ float np_dot256(const float* a, const float* b) {
    float A[4] = {0.f, 0.f, 0.f, 0.f};
#pragma unroll 4
    for (int t = 0; t < 16; t++) {
#pragma unroll
        for (int i = 3; i >= 0; i--) {
            const int base = 16 * t + 4 * i;
#pragma unroll
            for (int j = 0; j < 4; j++)
                A[j] = __fadd_rn(A[j], __fmul_rn(a[base + j], b[base + j]));
        }
    }
    return __fadd_rn(__fadd_rn(A[0], A[1]), __fadd_rn(A[2], A[3]));
}

__global__ __launch_bounds__(256) void cnorm_kernel(const float* __restrict__ c,
                                                    float* __restrict__ cn) {
    const int k = blockIdx.x * 256 + threadIdx.x;
    if (k < K) cn[k] = np_pw256_sq(c + (size_t)k * D);
}

__global__ __launch_bounds__(256) void fast_kernel(const float* __restrict__ x,
                                                   const float* __restrict__ c,
                                                   const float* __restrict__ cn,
                                                   float* __restrict__ out,
                                                   int* __restrict__ cnt,
                                                   int* __restrict__ list) {
    __shared__ float xT[TD][XPAD];   // [d][n] transposed: conflict-free reads
    __shared__ float cT[TD][CPAD];   // [d][k]
    __shared__ float xn_sh[TM];
    __shared__ float Lv1[4][TM];
    __shared__ int   Li1[4][TM];
    __shared__ float Lv2[4][TM];

    const int t    = threadIdx.x;
    const int wave = t >> 6;
    const int kk   = t & 3;
    const int rg   = (t >> 2) & 15;
    const int kb   = 4 * (4 * wave + kk);
    const int n0   = blockIdx.x * TM;

    if (t < TM) xn_sh[t] = np_pw256_sq(x + (size_t)(n0 + t) * D);
    __syncthreads();

    float xnr[4];
#pragma unroll
    for (int r = 0; r < 4; r++) xnr[r] = xn_sh[4 * rg + r];

    float v1[4], v2[4];
    int   i1[4];
#pragma unroll
    for (int r = 0; r < 4; r++) { v1[r] = -__builtin_inff(); v2[r] = -__builtin_inff(); i1[r] = 0; }

    for (int kc = 0; kc < K; kc += TK) {
        v2f acc[4][4];
#pragma unroll
        for (int r = 0; r < 4; r++)
#pragma unroll
            for (int j = 0; j < 4; j++) acc[r][j] = (v2f){0.f, 0.f};

        for (int dc = 0; dc < D; dc += TD) {
            {   // stage x tile (transpose 64 rows x 64 d)
                const int n = t >> 2, c4 = t & 3;
                const float* src = x + (size_t)(n0 + n) * D + dc;
#pragma unroll
                for (int i = 0; i < 4; i++) {
                    const int f = c4 + 4 * i;
                    const float4 v = ((const float4*)src)[f];
                    xT[4 * f + 0][n] = v.x;
                    xT[4 * f + 1][n] = v.y;
                    xT[4 * f + 2][n] = v.z;
                    xT[4 * f + 3][n] = v.w;
                }
            }
            {   // stage c tile (transpose 128 rows x 64 d)
                const int kr = t >> 1, c2 = t & 1;
                const float* src = c + (size_t)(kc + kr) * D + dc;
#pragma unroll
                for (int i = 0; i < 8; i++) {
                    const int f = c2 + 2 * i;
                    const float4 v = ((const float4*)src)[f];
                    cT[4 * f + 0][kr] = v.x;
                    cT[4 * f + 1][kr] = v.y;
                    cT[4 * f + 2][kr] = v.z;
                    cT[4 * f + 3][kr] = v.w;
                }
            }
            __syncthreads();

#pragma unroll 2
            for (int d = 0; d < TD; d++) {
                const float4 a  = *(const float4*)&xT[d][4 * rg];
                const float4 b0 = *(const float4*)&cT[d][kb];
                const float4 b1 = *(const float4*)&cT[d][kb + 64];
                const v2f b00 = {b0.x, b0.y}, b01 = {b0.z, b0.w};
                const v2f b10 = {b1.x, b1.y}, b11 = {b1.z, b1.w};
                const float av[4] = {a.x, a.y, a.z, a.w};
#pragma unroll
                for (int r = 0; r < 4; r++) {
                    const v2f ar = {av[r], av[r]};
                    acc[r][0] = __builtin_elementwise_fma(ar, b00, acc[r][0]);
                    acc[r][1] = __builtin_elementwise_fma(ar, b01, acc[r][1]);
                    acc[r][2] = __builtin_elementwise_fma(ar, b10, acc[r][2]);
                    acc[r][3] = __builtin_elementwise_fma(ar, b11, acc[r][3]);
                }
            }
            __syncthreads();
        }

        // chunk epilogue: fast sims, running top1/top2 per row (ascending k in-thread)
        float cnv[8];
#pragma unroll
        for (int j = 0; j < 4; j++) {
            cnv[j]     = cn[kc + kb + j];
            cnv[4 + j] = cn[kc + kb + 64 + j];
        }
#pragma unroll
        for (int r = 0; r < 4; r++) {
            const float dots[8] = {acc[r][0].x, acc[r][0].y, acc[r][1].x, acc[r][1].y,
                                   acc[r][2].x, acc[r][2].y, acc[r][3].x, acc[r][3].y};
#pragma unroll
            for (int j = 0; j < 8; j++) {
                const int kg = kc + kb + ((j < 4) ? j : 64 + (j - 4));
                const float v = 2.0f * dots[j] - xnr[r] - cnv[j];
                if (v > v1[r])      { v2[r] = v1[r]; v1[r] = v; i1[r] = kg; }
                else if (v > v2[r]) { v2[r] = v; }
                else if (v == v1[r]) { v2[r] = v; }  // exact tie -> margin 0
            }
        }
    }

    // merge across the 4 kk lanes
#pragma unroll
    for (int r = 0; r < 4; r++) {
#pragma unroll
        for (int m = 1; m <= 2; m <<= 1) {
            const float ov1 = __shfl_xor(v1[r], m);
            const int   oi1 = __shfl_xor(i1[r], m);
            const float ov2 = __shfl_xor(v2[r], m);
            if (ov1 > v1[r])      { v2[r] = fmaxf(v1[r], ov2); v1[r] = ov1; i1[r] = oi1; }
            else if (ov1 < v1[r]) { v2[r] = fmaxf(v2[r], ov1); }
            else                  { i1[r] = min(i1[r], oi1); v2[r] = v1[r]; }
        }
        if (kk == 0) {
            Lv1[wave][4 * rg + r] = v1[r];
            Li1[wave][4 * rg + r] = i1[r];
            Lv2[wave][4 * rg + r] = v2[r];
        }
    }
    __syncthreads();

    if (t < TM) {
        float bv1 = Lv1[0][t], bv2 = Lv2[0][t];
        int   bi  = Li1[0][t];
#pragma unroll
        for (int w = 1; w < 4; w++) {
            const float ov1 = Lv1[w][t], ov2 = Lv2[w][t];
            const int   oi1 = Li1[w][t];
            if (ov1 > bv1)      { bv2 = fmaxf(bv1, ov2); bv1 = ov1; bi = oi1; }
            else if (ov1 < bv1) { bv2 = fmaxf(bv2, ov1); }
            else                { bi = min(bi, oi1); bv2 = bv1; }
        }
        const int row = n0 + t;
        if (bv1 - bv2 >= EPS) {
            // np winner provably unique & == bi: emit np-bit-exact value
            const float dot = np_dot256(x + (size_t)row * D, c + (size_t)bi * D);
            const float v = __fsub_rn(__fsub_rn(__fmul_rn(2.0f, dot), xn_sh[t]), cn[bi]);
            out[row]     = v;
            out[N + row] = (float)bi;
        } else {
            const int pos = atomicAdd(cnt, 1);
            list[pos] = row;
        }
    }
}

__global__ __launch_bounds__(256) void fallback_kernel(const float* __restrict__ x,
                                                       const float* __restrict__ c,
                                                       const float* __restrict__ cn,
                                                       float* __restrict__ out,
                                                       const int* __restrict__ cnt,
                                                       const int* __restrict__ list) {
    __shared__ float xrow[D];
    __shared__ float xn_s;
    __shared__ float wv[4];
    __shared__ int   wi[4];
    const int tid = threadIdx.x, lane = tid & 63, w = tid >> 6;
    const int total = *cnt;
    for (int idx = blockIdx.x; idx < total; idx += gridDim.x) {
        const int row = list[idx];
        if (tid < 64) *(float4*)&xrow[4 * tid] = ((const float4*)(x + (size_t)row * D))[tid];
        __syncthreads();
        if (tid == 0) xn_s = np_pw256_sq(xrow);
        __syncthreads();
        const float xn = xn_s;
        float bv = -__builtin_inff();
        int   bi = 0;
#pragma unroll
        for (int j = 0; j < 4; j++) {
            const int k = 4 * tid + j;  // ascending within thread
            const float dot = np_dot256(xrow, c + (size_t)k * D);
            const float v = __fsub_rn(__fsub_rn(__fmul_rn(2.0f, dot), xn), cn[k]);
            if (v > bv) { bv = v; bi = k; }
        }
#pragma unroll
        for (int m = 1; m <= 32; m <<= 1) {
            const float ov = __shfl_xor(bv, m);
            const int   oi = __shfl_xor(bi, m);
            if (ov > bv || (ov == bv && oi < bi)) { bv = ov; bi = oi; }
        }
        if (lane == 0) { wv[w] = bv; wi[w] = bi; }
        __syncthreads();
        if (tid == 0) {
#pragma unroll
            for (int ww = 1; ww < 4; ww++) {
                if (wv[ww] > bv || (wv[ww] == bv && wi[ww] < bi)) { bv = wv[ww]; bi = wi[ww]; }
            }
            out[row]     = bv;
            out[N + row] = (float)bi;
        }
        __syncthreads();
    }
}

extern "C" void kernel_launch(void* const* d_in, const int* in_sizes, int n_in,
                              void* d_out, int out_size, void* d_ws, size_t ws_size,
                              hipStream_t stream) {
    const float* x = (const float*)d_in[0];
    const float* c = (const float*)d_in[1];
    float* out     = (float*)d_out;
    // ws layout: [0,4096) cn | [4096,4100) count | [4608, ...) flagged-row list (N ints)
    float* cn  = (float*)d_ws;
    int* cnt   = (int*)((char*)d_ws + 4096);
    int* list  = (int*)((char*)d_ws + 4608);

    hipMemsetAsync(cnt, 0, sizeof(int), stream);
    cnorm_kernel<<<(K + 255) / 256, 256, 0, stream>>>(c, cn);
    fast_kernel<<<N / TM, 256, 0, stream>>>(x, c, cn, out, cnt, list);
    fallback_kernel<<<512, 256, 0, stream>>>(x, c, cn, out, cnt, list);
}

// Round 8
// 1242.330 us; speedup vs baseline: 1.8149x; 1.3715x over previous
//
#include <hip/hip_runtime.h>

// Nearest-centroid assignment. out[0..N) = max_sim (float), out[N..2N) = argmax (as float).
//
// Decision semantics = round-6 validated np bit-model (einsum baseline-SSE3 unfused
// cascade + AVX512F pairwise norms + fl32 chain + first-max). Fast fp32-FMA GEMM
// tracks top1(value,index)+top2(value); margin >= EPS -> winner provably = np winner,
// recompute its sim np-bit-exactly; margin < EPS -> row -> fallback (full np-exact).
constexpr int N = 131072;
constexpr int D = 256;
constexpr int K = 1024;

constexpr int TM = 128;   // rows per block
constexpr int TK = 128;   // centroids per chunk
constexpr int TD = 32;    // depth per stage
constexpr int PAD = 129;  // leading dim pad (TM+1 == TK+1)
constexpr float EPS = 0.08f;

__device__ __forceinline__ float sqf(float a) { return __fmul_rn(a, a); }

// numpy AVX512F pairwise base case over 128 contiguous squares.
__device__ __forceinline__ float np_sumsq128(const float* q) {
    float lane[16];
#pragma unroll
    for (int j = 0; j < 16; j++) {
        const float r0 = __fadd_rn(sqf(q[j]),      sqf(q[64 + j]));
        const float r1 = __fadd_rn(sqf(q[16 + j]), sqf(q[80 + j]));
        const float r2 = __fadd_rn(sqf(q[32 + j]), sqf(q[96 + j]));
        const float r3 = __fadd_rn(sqf(q[48 + j]), sqf(q[112 + j]));
        lane[j] = __fadd_rn(__fadd_rn(r0, r1), __fadd_rn(r2, r3));
    }
    float t[8];
#pragma unroll
    for (int i = 0; i < 8; i++) t[i] = __fadd_rn(lane[i], lane[i + 8]);
    float u[4];
#pragma unroll
    for (int i = 0; i < 4; i++) u[i] = __fadd_rn(t[i], t[i + 4]);
    return __fadd_rn(__fadd_rn(u[0], u[2]), __fadd_rn(u[1], u[3]));
}
__device__ __forceinline__ float np_pw256_sq(const float* p) {
    return __fadd_rn(np_sumsq128(p), np_sumsq128(p + 128));
}

// np einsum bit-exact dot over 256 contiguous floats.
__device__ __forceinline__ float np_dot256(const float* a, const float* b) {
    float A[4] = {0.f, 0.f, 0.f, 0.f};
#pragma unroll 4
    for (int t = 0; t < 16; t++) {
#pragma unroll
        for (int i = 3; i >= 0; i--) {
            const int base = 16 * t + 4 * i;
#pragma unroll
            for (int j = 0; j < 4; j++)
                A[j] = __fadd_rn(A[j], __fmul_rn(a[base + j], b[base + j]));
        }
    }
    return __fadd_rn(__fadd_rn(A[0], A[1]), __fadd_rn(A[2], A[3]));
}

__global__ __launch_bounds__(256) void cnorm_kernel(const float* __restrict__ c,
                                                    float* __restrict__ cn) {
    const int k = blockIdx.x * 256 + threadIdx.x;
    if (k < K) cn[k] = np_pw256_sq(c + (size_t)k * D);
}

__global__ __launch_bounds__(256, 3) void fast_kernel(const float* __restrict__ x,
                                                      const float* __restrict__ c,
                                                      const float* __restrict__ cn,
                                                      float* __restrict__ out,
                                                      int* __restrict__ cnt,
                                                      int* __restrict__ list) {
    __shared__ float xT[TD][PAD];   // [d][row], transposed
    __shared__ float cT[TD][PAD];   // [d][k],   transposed
    __shared__ float xn_sh[TM];
    __shared__ int   rbi[TM];
    __shared__ int   rok[TM];

    const int t  = threadIdx.x;
    const int tx = t & 15;    // k-dim thread coord (low 4 lane bits)
    const int ty = t >> 4;    // row-dim thread coord
    const int n0 = blockIdx.x * TM;

    if (t < TM) xn_sh[t] = np_pw256_sq(x + (size_t)(n0 + t) * D);
    __syncthreads();

    // per-thread rows: {4ty+i, 64+4ty+i}; ks per chunk: {4tx+j, 64+4tx+j}
    float xnr[2][4];
#pragma unroll
    for (int rh = 0; rh < 2; rh++)
#pragma unroll
        for (int i = 0; i < 4; i++) xnr[rh][i] = xn_sh[64 * rh + 4 * ty + i];

    float v1[2][4], v2[2][4];
    int   i1[2][4];
#pragma unroll
    for (int rh = 0; rh < 2; rh++)
#pragma unroll
        for (int i = 0; i < 4; i++) {
            v1[rh][i] = -__builtin_inff(); v2[rh][i] = -__builtin_inff(); i1[rh][i] = 0;
        }

    const int srow = t >> 1;       // staging row [0,128)
    const int shf  = t & 1;        // staging half (16 floats each)

    for (int kc = 0; kc < K; kc += TK) {
        float acc[2][2][4][4];     // [rh][kh][i][j]
#pragma unroll
        for (int rh = 0; rh < 2; rh++)
#pragma unroll
            for (int kh = 0; kh < 2; kh++)
#pragma unroll
                for (int i = 0; i < 4; i++)
#pragma unroll
                    for (int j = 0; j < 4; j++) acc[rh][kh][i][j] = 0.f;

        for (int dc = 0; dc < D; dc += TD) {
            {   // stage x tile (transpose 128 rows x 32 d)
                const float* src = x + (size_t)(n0 + srow) * D + dc + 16 * shf;
                const int db = 16 * shf;
#pragma unroll
                for (int a = 0; a < 4; a++) {
                    const float4 v = ((const float4*)src)[a];
                    xT[db + 4 * a + 0][srow] = v.x;
                    xT[db + 4 * a + 1][srow] = v.y;
                    xT[db + 4 * a + 2][srow] = v.z;
                    xT[db + 4 * a + 3][srow] = v.w;
                }
            }
            {   // stage c tile (transpose 128 k x 32 d)
                const float* src = c + (size_t)(kc + srow) * D + dc + 16 * shf;
                const int db = 16 * shf;
#pragma unroll
                for (int a = 0; a < 4; a++) {
                    const float4 v = ((const float4*)src)[a];
                    cT[db + 4 * a + 0][srow] = v.x;
                    cT[db + 4 * a + 1][srow] = v.y;
                    cT[db + 4 * a + 2][srow] = v.z;
                    cT[db + 4 * a + 3][srow] = v.w;
                }
            }
            __syncthreads();

#pragma unroll 4
            for (int d = 0; d < TD; d++) {
                const float4 a0 = *(const float4*)&xT[d][4 * ty];
                const float4 a1 = *(const float4*)&xT[d][64 + 4 * ty];
                const float4 b0 = *(const float4*)&cT[d][4 * tx];
                const float4 b1 = *(const float4*)&cT[d][64 + 4 * tx];
                const float av[2][4] = {{a0.x, a0.y, a0.z, a0.w}, {a1.x, a1.y, a1.z, a1.w}};
                const float bv[2][4] = {{b0.x, b0.y, b0.z, b0.w}, {b1.x, b1.y, b1.z, b1.w}};
#pragma unroll
                for (int rh = 0; rh < 2; rh++)
#pragma unroll
                    for (int kh = 0; kh < 2; kh++)
#pragma unroll
                        for (int i = 0; i < 4; i++)
#pragma unroll
                            for (int j = 0; j < 4; j++)
                                acc[rh][kh][i][j] = fmaf(av[rh][i], bv[kh][j], acc[rh][kh][i][j]);
            }
            __syncthreads();
        }

        // chunk epilogue: ascending kg per thread (kh then j)
#pragma unroll
        for (int kh = 0; kh < 2; kh++)
#pragma unroll
            for (int j = 0; j < 4; j++) {
                const int kg = kc + 64 * kh + 4 * tx + j;
                const float cnj = cn[kg];
#pragma unroll
                for (int rh = 0; rh < 2; rh++)
#pragma unroll
                    for (int i = 0; i < 4; i++) {
                        const float v = 2.0f * acc[rh][kh][i][j] - xnr[rh][i] - cnj;
                        if (v > v1[rh][i])       { v2[rh][i] = v1[rh][i]; v1[rh][i] = v; i1[rh][i] = kg; }
                        else if (v > v2[rh][i])  { v2[rh][i] = v; }
                        else if (v == v1[rh][i]) { v2[rh][i] = v; }  // exact tie -> margin 0
                    }
            }
    }

    // merge across tx lanes (low 4 lane bits) per row, then decide
#pragma unroll
    for (int rh = 0; rh < 2; rh++)
#pragma unroll
        for (int i = 0; i < 4; i++) {
            float a1v = v1[rh][i], a2v = v2[rh][i];
            int   ai  = i1[rh][i];
#pragma unroll
            for (int m = 1; m <= 8; m <<= 1) {
                const float ov1 = __shfl_xor(a1v, m);
                const int   oi  = __shfl_xor(ai, m);
                const float ov2 = __shfl_xor(a2v, m);
                if (ov1 > a1v)      { a2v = fmaxf(a1v, ov2); a1v = ov1; ai = oi; }
                else if (ov1 < a1v) { a2v = fmaxf(a2v, ov1); }
                else                { ai = min(ai, oi); a2v = a1v; }
            }
            if (tx == 0) {
                const int row = 64 * rh + 4 * ty + i;
                const int ok = (a1v - a2v >= EPS) ? 1 : 0;
                rbi[row] = ai;
                rok[row] = ok;
                if (!ok) { const int pos = atomicAdd(cnt, 1); list[pos] = n0 + row; }
            }
        }
    __syncthreads();

    if (t < TM && rok[t]) {
        const int row = n0 + t;
        const int bi  = rbi[t];
        const float dot = np_dot256(x + (size_t)row * D, c + (size_t)bi * D);
        const float v = __fsub_rn(__fsub_rn(__fmul_rn(2.0f, dot), xn_sh[t]), cn[bi]);
        out[row]     = v;
        out[N + row] = (float)bi;
    }
}

__global__ __launch_bounds__(256) void fallback_kernel(const float* __restrict__ x,
                                                       const float* __restrict__ c,
                                                       const float* __restrict__ cn,
                                                       float* __restrict__ out,
                                                       const int* __restrict__ cnt,
                                                       const int* __restrict__ list) {
    __shared__ float xrow[D];
    __shared__ float xn_s;
    __shared__ float wv[4];
    __shared__ int   wi[4];
    const int tid = threadIdx.x, lane = tid & 63, w = tid >> 6;
    const int total = *cnt;
    for (int idx = blockIdx.x; idx < total; idx += gridDim.x) {
        const int row = list[idx];
        if (tid < 64) *(float4*)&xrow[4 * tid] = ((const float4*)(x + (size_t)row * D))[tid];
        __syncthreads();
        if (tid == 0) xn_s = np_pw256_sq(xrow);
        __syncthreads();
        const float xn = xn_s;
        float bv = -__builtin_inff();
        int   bi = 0;
#pragma unroll
        for (int j = 0; j < 4; j++) {
            const int k = 4 * tid + j;  // ascending within thread
            const float dot = np_dot256(xrow, c + (size_t)k * D);
            const float v = __fsub_rn(__fsub_rn(__fmul_rn(2.0f, dot), xn), cn[k]);
            if (v > bv) { bv = v; bi = k; }
        }
#pragma unroll
        for (int m = 1; m <= 32; m <<= 1) {
            const float ov = __shfl_xor(bv, m);
            const int   oi = __shfl_xor(bi, m);
            if (ov > bv || (ov == bv && oi < bi)) { bv = ov; bi = oi; }
        }
        if (lane == 0) { wv[w] = bv; wi[w] = bi; }
        __syncthreads();
        if (tid == 0) {
#pragma unroll
            for (int ww = 1; ww < 4; ww++) {
                if (wv[ww] > bv || (wv[ww] == bv && wi[ww] < bi)) { bv = wv[ww]; bi = wi[ww]; }
            }
            out[row]     = bv;
            out[N + row] = (float)bi;
        }
        __syncthreads();
    }
}

extern "C" void kernel_launch(void* const* d_in, const int* in_sizes, int n_in,
                              void* d_out, int out_size, void* d_ws, size_t ws_size,
                              hipStream_t stream) {
    const float* x = (const float*)d_in[0];
    const float* c = (const float*)d_in[1];
    float* out     = (float*)d_out;
    // ws layout: [0,4096) cn | [4096,4100) count | [4608, ...) flagged-row list
    float* cn = (float*)d_ws;
    int* cnt  = (int*)((char*)d_ws + 4096);
    int* list = (int*)((char*)d_ws + 4608);

    hipMemsetAsync(cnt, 0, sizeof(int), stream);
    cnorm_kernel<<<(K + 255) / 256, 256, 0, stream>>>(c, cn);
    fast_kernel<<<N / TM, 256, 0, stream>>>(x, c, cn, out, cnt, list);
    fallback_kernel<<<512, 256, 0, stream>>>(x, c, cn, out, cnt, list);
}